// Round 3
// baseline (196.974 us; speedup 1.0000x reference)
//
#include <hip/hip_runtime.h>

// The reference, as literally written, is degenerate:
//   k/v carry a singleton head axis; einsum('bhqd,bskd->bhqk') sums away the
//   key-position axis 's' and leaves a size-1 'k' axis; jnp.where broadcasts
//   it across the causal mask, so every softmax row is constant -> exactly
//   uniform weights. Q, K, RoPE, and causality all cancel:
//     out[b,t,n] = sum_d V_sum[b,d] * (sum_h Wo[64h+d, n]) + bo[n]
//   with V_sum[b,:] = (sum_t x[b,t,:]) @ Wv + T*bv  -- constant over t.
// Verified in R2 (passed, absmax 0.0625). This round: 5 dispatches -> 3,
// no atomics, no memset, biases folded upstream.

namespace {
constexpr int B   = 8;
constexpr int T   = 1000;
constexpr int D   = 1024;
constexpr int HD  = 64;
constexpr int TSZ = 16;                    // t-rows per K1 block
constexpr int NSEG = (T + TSZ - 1) / TSZ;  // 63
}

// ---------------------------------------------------------------------------
// K1: partial[(seg*B+b)*D + c] = sum_{t in seg} x[b,t,c]     (no atomics)
// grid (NSEG, B) x 256 threads, float4 per thread.
// ---------------------------------------------------------------------------
__global__ __launch_bounds__(256)
void xsum_part_kernel(const float* __restrict__ x, float* __restrict__ partial)
{
    const int seg = blockIdx.x;
    const int b   = blockIdx.y;
    const int t0  = seg * TSZ;
    const int tn  = min(TSZ, T - t0);
    const int c4  = threadIdx.x * 4;
    float4 acc = make_float4(0.f, 0.f, 0.f, 0.f);
    const float* base = x + ((size_t)b * T + t0) * D + c4;
    for (int i = 0; i < tn; ++i) {
        const float4 v = *(const float4*)(base + (size_t)i * D);
        acc.x += v.x; acc.y += v.y; acc.z += v.z; acc.w += v.w;
    }
    *(float4*)(partial + ((size_t)seg * B + b) * D + c4) = acc;
}

// ---------------------------------------------------------------------------
// K2: 32 blocks. Stage A: reduce partials -> xs (LDS). Stage B: vs = xs@Wv
// + T*bv (LDS). Stage C: ro[b][n0..n0+31] = vs[b,:] . WoH[:,n-slice] + bo[n],
// where WoH[d][n] = sum_h Wo[64h+d][n] (computed implicitly via k&63).
// Exclusive n-slices -> no atomics.
// ---------------------------------------------------------------------------
__global__ __launch_bounds__(256)
void mid_kernel(const float* __restrict__ partial, const float* __restrict__ Wv,
                const float* __restrict__ bv, const float* __restrict__ Wo,
                const float* __restrict__ bo, float* __restrict__ ro)
{
    __shared__ float xs_l[B * D];          // 32 KB
    __shared__ float vs_l[B][HD];          // 2 KB
    const int t = threadIdx.x;

    // --- Stage A: xs[j] = sum_seg partial[seg*8192 + j], float4 per thread ---
    for (int idx4 = t; idx4 < (B * D) / 4; idx4 += 256) {
        float4 acc = make_float4(0.f, 0.f, 0.f, 0.f);
        const float* p = partial + idx4 * 4;
        for (int s = 0; s < NSEG; ++s) {
            const float4 v = *(const float4*)(p + (size_t)s * (B * D));
            acc.x += v.x; acc.y += v.y; acc.z += v.z; acc.w += v.w;
        }
        *(float4*)&xs_l[idx4 * 4] = acc;
    }
    __syncthreads();

    // --- Stage B: vs[b][d] = xs[b,:] . Wv[:,d] + T*bv[d]  (2 outputs/thr) ---
    {
        const int d = t & 63;
        const int b0 = t >> 6;             // 0..3; also handles b0+4
        float a0 = 0.f, a1 = 0.f;
        for (int c = 0; c < D; ++c) {
            const float w = Wv[(size_t)c * HD + d];
            a0 = fmaf(xs_l[b0 * D + c], w, a0);
            a1 = fmaf(xs_l[(b0 + 4) * D + c], w, a1);
        }
        const float bias = (float)T * bv[d];
        vs_l[b0][d]     = a0 + bias;
        vs_l[b0 + 4][d] = a1 + bias;
    }
    __syncthreads();

    // --- Stage C: ro slice (32 n-cols per block, 8 b per col) ---
    {
        const int n = blockIdx.x * 32 + (t & 31);
        const int b = t >> 5;
        float acc = bo[n];
        for (int k = 0; k < D; ++k)
            acc = fmaf(vs_l[b][k & 63], Wo[(size_t)k * D + n], acc);
        ro[b * D + n] = acc;
    }
}

// ---------------------------------------------------------------------------
// K3: out[b,t,:] = ro[b,:]   (pure broadcast, bo already folded)
// ---------------------------------------------------------------------------
__global__ __launch_bounds__(256)
void bcast_kernel(const float* __restrict__ ro, float* __restrict__ out)
{
    const int t  = blockIdx.x;
    const int b  = blockIdx.y;
    const int c4 = threadIdx.x * 4;
    const float4 r = *(const float4*)(ro + b * D + c4);
    *(float4*)(out + ((size_t)b * T + t) * D + c4) = r;
}

// ---------------------------------------------------------------------------
extern "C" void kernel_launch(void* const* d_in, const int* in_sizes, int n_in,
                              void* d_out, int out_size, void* d_ws, size_t ws_size,
                              hipStream_t stream)
{
    const float* x  = (const float*)d_in[0];
    const float* Wv = (const float*)d_in[5];
    const float* bv = (const float*)d_in[6];
    const float* Wo = (const float*)d_in[7];
    const float* bo = (const float*)d_in[8];
    float* out = (float*)d_out;

    // ws layout (floats): partial[NSEG*B*D] (~8.3 MB) | ro[B*D]
    float* partial = (float*)d_ws;
    float* ro      = partial + (size_t)NSEG * B * D;

    xsum_part_kernel<<<dim3(NSEG, B), 256, 0, stream>>>(x, partial);
    mid_kernel      <<<dim3(32),      256, 0, stream>>>(partial, Wv, bv, Wo, bo, ro);
    bcast_kernel    <<<dim3(T, B),    256, 0, stream>>>(ro, out);
}

// Round 4
// 145.170 us; speedup vs baseline: 1.3568x; 1.3568x over previous
//
#include <hip/hip_runtime.h>

// The reference, as literally written, is degenerate:
//   k/v carry a singleton head axis; einsum('bhqd,bskd->bhqk') sums away the
//   key-position axis 's' and leaves a size-1 'k' axis; jnp.where broadcasts
//   it across the causal mask -> softmax rows are exactly uniform. Q, K, RoPE,
//   and causality all cancel:
//     out[b,t,n] = sum_d V_sum[b,d] * WoH[d,n] + bo[n]      (constant over t)
//     V_sum[b,:] = (sum_t x[b,t,:]) @ Wv + T*bv
//     WoH[d,n]   = sum_h Wo[64h+d, n]
// Verified R2 (passed, absmax 0.0625). R3 post-mortem: 32-block fused kernel
// with 1024-deep serial load loops was latency-bound (113 us, occ 1.4%).
// R4: many threads, all serial loops <= 64 deep, no atomics, 4 dispatches.

namespace {
constexpr int B   = 8;
constexpr int T   = 1000;
constexpr int D   = 1024;
constexpr int HD  = 64;
constexpr int TSZ = 16;                    // t-rows per K1 block
constexpr int NSEG = (T + TSZ - 1) / TSZ;  // 63
}

// ---------------------------------------------------------------------------
// K1: partial[(seg*B+b)*D + c] = sum_{t in seg} x[b,t,c]   (504 blocks)
// ---------------------------------------------------------------------------
__global__ __launch_bounds__(256)
void xsum_part_kernel(const float* __restrict__ x, float* __restrict__ partial)
{
    const int seg = blockIdx.x;
    const int b   = blockIdx.y;
    const int t0  = seg * TSZ;
    const int tn  = min(TSZ, T - t0);
    const int c4  = threadIdx.x * 4;
    float4 acc = make_float4(0.f, 0.f, 0.f, 0.f);
    const float* base = x + ((size_t)b * T + t0) * D + c4;
    for (int i = 0; i < tn; ++i) {
        const float4 v = *(const float4*)(base + (size_t)i * D);
        acc.x += v.x; acc.y += v.y; acc.z += v.z; acc.w += v.w;
    }
    *(float4*)(partial + ((size_t)seg * B + b) * D + c4) = acc;
}

// ---------------------------------------------------------------------------
// K2: blocks 0..31  -> xs[j] = sum_seg partial[...]    (63-deep, unrolled)
//     blocks 32..287-> WoH[d*1024+n] = sum_h Wo[(64h+d)*1024+n] (16-deep)
// ---------------------------------------------------------------------------
__global__ __launch_bounds__(256)
void reduce_kernel(const float* __restrict__ partial, const float* __restrict__ Wo,
                   float* __restrict__ xs, float* __restrict__ WoH)
{
    const int blk = blockIdx.x;
    if (blk < 32) {
        const int j = blk * 256 + threadIdx.x;          // 0..8191
        float acc = 0.f;
        #pragma unroll
        for (int s = 0; s < NSEG; ++s)
            acc += partial[(size_t)s * (B * D) + j];
        xs[j] = acc;
    } else {
        const int idx = (blk - 32) * 256 + threadIdx.x; // 0..65535
        const int d = idx >> 10, n = idx & 1023;
        float acc = 0.f;
        #pragma unroll
        for (int h = 0; h < 16; ++h)
            acc += Wo[(size_t)(h * HD + d) * D + n];    // coalesced over n
        WoH[idx] = acc;
    }
}

// ---------------------------------------------------------------------------
// K3: vsp[kc][b][d] = sum_{c in kc-chunk} xs[b,c]*Wv[c,d]  (+T*bv at kc==0)
// grid (4, 8); 64-deep loop; LDS reduce over 4 sub-chunks; no atomics.
// ---------------------------------------------------------------------------
__global__ __launch_bounds__(256)
void vs_kernel(const float* __restrict__ xs, const float* __restrict__ Wv,
               const float* __restrict__ bv, float* __restrict__ vsp)
{
    __shared__ float xsl[256];
    __shared__ float part[4][HD];
    const int kc = blockIdx.x;                 // 0..3 (K chunk of 256)
    const int b  = blockIdx.y;
    const int t  = threadIdx.x;
    const int d  = t & 63, sub = t >> 6;       // sub-chunk of 64
    xsl[t] = xs[b * D + kc * 256 + t];
    __syncthreads();
    const int c0 = kc * 256 + sub * 64;
    float acc = 0.f;
    #pragma unroll
    for (int i = 0; i < 64; ++i)
        acc = fmaf(xsl[sub * 64 + i], Wv[(size_t)(c0 + i) * HD + d], acc);
    part[sub][d] = acc;
    __syncthreads();
    if (sub == 0) {
        float v = part[0][d] + part[1][d] + part[2][d] + part[3][d];
        if (kc == 0) v += (float)T * bv[d];
        vsp[(kc * B + b) * HD + d] = v;
    }
}

// ---------------------------------------------------------------------------
// K4: ro slice + broadcast.  grid (4 n-quarters, 8 b, 8 t-chunks).
// Each block: reduce vsp -> vs2 (LDS), compute 256-col ro slice (64-deep over
// WoH, bo folded), write 125 rows of out as float4.
// ---------------------------------------------------------------------------
__global__ __launch_bounds__(256)
void out_kernel(const float* __restrict__ vsp, const float* __restrict__ WoH,
                const float* __restrict__ bo, float* __restrict__ out)
{
    __shared__ float vl[256];
    __shared__ float vs2[HD];
    __shared__ float rosl[256];
    const int nq = blockIdx.x;                 // 0..3
    const int b  = blockIdx.y;                 // 0..7
    const int tz = blockIdx.z;                 // 0..7
    const int t  = threadIdx.x;

    {   // gather the 4 split-K partials for this b
        const int p = t >> 6, d = t & 63;
        vl[t] = vsp[(p * B + b) * HD + d];
    }
    __syncthreads();
    if (t < HD)
        vs2[t] = vl[t] + vl[64 + t] + vl[128 + t] + vl[192 + t];
    __syncthreads();

    const int n = nq * 256 + t;
    float acc = bo[n];
    #pragma unroll
    for (int d = 0; d < HD; ++d)
        acc = fmaf(vs2[d], WoH[d * D + n], acc);   // vs2: LDS broadcast
    rosl[t] = acc;
    __syncthreads();

    const int t0 = tz * 125;
    const int f4 = t & 63;                     // constant per thread
    const float4 val = *(const float4*)&rosl[f4 * 4];
    for (int idx = t; idx < 125 * 64; idx += 256) {
        const int r = idx >> 6;
        *(float4*)(out + ((size_t)b * T + t0 + r) * D + nq * 256 + f4 * 4) = val;
    }
}

// ---------------------------------------------------------------------------
extern "C" void kernel_launch(void* const* d_in, const int* in_sizes, int n_in,
                              void* d_out, int out_size, void* d_ws, size_t ws_size,
                              hipStream_t stream)
{
    const float* x  = (const float*)d_in[0];
    const float* Wv = (const float*)d_in[5];
    const float* bv = (const float*)d_in[6];
    const float* Wo = (const float*)d_in[7];
    const float* bo = (const float*)d_in[8];
    float* out = (float*)d_out;

    // ws layout (floats): partial[63*8*1024] | xs[8192] | WoH[65536] | vsp[2048]
    float* partial = (float*)d_ws;
    float* xs  = partial + (size_t)NSEG * B * D;
    float* WoH = xs + B * D;
    float* vsp = WoH + HD * D;

    xsum_part_kernel<<<dim3(NSEG, B), 256, 0, stream>>>(x, partial);
    reduce_kernel   <<<dim3(32 + 256), 256, 0, stream>>>(partial, Wo, xs, WoH);
    vs_kernel       <<<dim3(4, B),     256, 0, stream>>>(xs, Wv, bv, vsp);
    out_kernel      <<<dim3(4, B, 8),  256, 0, stream>>>(vsp, WoH, bo, out);
}